// Round 11
// baseline (1612.053 us; speedup 1.0000x reference)
//
#include <hip/hip_runtime.h>
#include <hip/hip_bf16.h>
#include <cstddef>
#include <cstdint>

#define BATCH 16
#define NPTS  4096
#define MPTS  1024
#define PTOT  65536
#define C1    128
#define C2    256
#define NBLK  1024

typedef short bf16x8 __attribute__((ext_vector_type(8)));
typedef float f32x4  __attribute__((ext_vector_type(4)));
typedef unsigned int u32x4 __attribute__((ext_vector_type(4)));

static __device__ __forceinline__ float bf2f(unsigned int u16) {
    union { unsigned int i; float f; } v; v.i = u16 << 16; return v.f;
}
static __device__ __forceinline__ unsigned short f2bf(float f) {
    union { float f; unsigned int i; } v; v.f = f;
    unsigned int u = v.i;
    return (unsigned short)((u + 0x7FFFu + ((u >> 16) & 1u)) >> 16);
}

static __device__ __forceinline__ float aload(const float* p) {
    return __hip_atomic_load(p, __ATOMIC_RELAXED, __HIP_MEMORY_SCOPE_AGENT);
}
static __device__ __forceinline__ void astore(float* p, float v) {
    __hip_atomic_store(p, v, __ATOMIC_RELAXED, __HIP_MEMORY_SCOPE_AGENT);
}

// ---------------------------------------------------------------------------
// Hierarchical sense-reversing grid barrier. 1024 blocks = 16 groups x 64.
// Generation-relative (works from any initial gen); counters must start 0
// (hipMemsetAsync at launch). Agent-scope atomics; ACQ_REL chain gives
// release->acquire transitivity for data written before the barrier.
// ---------------------------------------------------------------------------
static __device__ __forceinline__ void gsync(unsigned* bar) {
    __threadfence();
    __syncthreads();
    if (threadIdx.x == 0) {
        unsigned* grp  = bar + (blockIdx.x & 15) * 16;
        unsigned* root = bar + 256;
        unsigned* gen  = bar + 272;
        unsigned g = __hip_atomic_load(gen, __ATOMIC_RELAXED, __HIP_MEMORY_SCOPE_AGENT);
        if (__hip_atomic_fetch_add(grp, 1u, __ATOMIC_ACQ_REL, __HIP_MEMORY_SCOPE_AGENT) == 63u) {
            __hip_atomic_store(grp, 0u, __ATOMIC_RELAXED, __HIP_MEMORY_SCOPE_AGENT);
            if (__hip_atomic_fetch_add(root, 1u, __ATOMIC_ACQ_REL, __HIP_MEMORY_SCOPE_AGENT) == 15u) {
                __hip_atomic_store(root, 0u, __ATOMIC_RELAXED, __HIP_MEMORY_SCOPE_AGENT);
                __hip_atomic_fetch_add(gen, 1u, __ATOMIC_RELEASE, __HIP_MEMORY_SCOPE_AGENT);
            }
        }
        while (__hip_atomic_load(gen, __ATOMIC_ACQUIRE, __HIP_MEMORY_SCOPE_AGENT) == g)
            __builtin_amdgcn_s_sleep(2);
    }
    __syncthreads();
}

// ---------------------------------------------------------------------------
// Prep kernels (unchanged from r6)
// ---------------------------------------------------------------------------
__global__ void k_transpose0(const float* __restrict__ in, unsigned short* __restrict__ out,
                             int C, int N) {
    __shared__ float tile[64][65];
    int b  = blockIdx.z;
    int n0 = blockIdx.x * 64;
    int c0 = blockIdx.y * 64;
    const float* src = in + (size_t)b * C * N;
    unsigned short* dst = out + (size_t)b * N * C;
    int t  = threadIdx.x;
    int t4 = t >> 6, tn = t & 63;
#pragma unroll
    for (int i = 0; i < 16; ++i) {
        int cc = i * 4 + t4;
        tile[cc][tn] = src[(size_t)(c0 + cc) * N + n0 + tn];
    }
    __syncthreads();
#pragma unroll
    for (int i = 0; i < 16; ++i) {
        int nn = i * 4 + t4;
        dst[(size_t)(n0 + nn) * C + c0 + tn] = f2bf(tile[tn][nn]);
    }
}

__global__ void k_cvt_pack(const float* __restrict__ in, unsigned short* __restrict__ out, int K) {
    int tid = blockIdx.x * 256 + threadIdx.x;
    if (tid >= 256 * K) return;
    int ch = tid / K, k = tid % K;
    int ks = k >> 5, lhi = (k >> 3) & 3, e = k & 7;
    int wv = ch >> 6, i = (ch >> 4) & 3, llo = ch & 15;
    int lane = lhi * 16 + llo;
    out[((size_t)((ks * 16 + wv * 4 + i) * 64 + lane)) * 8 + e] = f2bf(in[tid]);
}

static __device__ __forceinline__ bool nn_less(float da, int ia, float db, int ib) {
    return (da < db) || (da == db && ia < ib);
}

__global__ void k_three_nn(const float* __restrict__ unknown, const float* __restrict__ known,
                           int* __restrict__ idx_out, float* __restrict__ w_out) {
    __shared__ float4 kpt[MPTS + 4];
    int t  = threadIdx.x;
    int p0 = blockIdx.x * 64;
    int b  = p0 >> 12;
    const float* kb = known + (size_t)b * MPTS * 3;
    for (int i = t; i < MPTS; i += 256) {
        float x = kb[i * 3 + 0], y = kb[i * 3 + 1], z = kb[i * 3 + 2];
        float dd = __fadd_rn(__fadd_rn(__fmul_rn(x, x), __fmul_rn(y, y)), __fmul_rn(z, z));
        float4 v; v.x = x; v.y = y; v.z = z; v.w = dd;
        kpt[i + (i >> 8)] = v;
    }
    __syncthreads();
    int q = t & 3;
    int p = p0 + (t >> 2);
    const float* up = unknown + (size_t)p * 3;
    float ux = up[0], uy = up[1], uz = up[2];
    float u2 = __fadd_rn(__fadd_rn(__fmul_rn(ux, ux), __fmul_rn(uy, uy)), __fmul_rn(uz, uz));
    float d0 = INFINITY, d1 = INFINITY, d2 = INFINITY;
    int   i0 = 0, i1 = 0, i2 = 0;
    int base = q * 257;
#pragma unroll 4
    for (int it = 0; it < 256; ++it) {
        float4 kp = kpt[base + it];
        float dot = __fadd_rn(__fadd_rn(__fmul_rn(ux, kp.x), __fmul_rn(uy, kp.y)),
                              __fmul_rn(uz, kp.z));
        float d = __fsub_rn(__fadd_rn(u2, kp.w), __fmul_rn(2.0f, dot));
        int k = q * 256 + it;
        if (d < d0)      { d2 = d1; i2 = i1; d1 = d0; i1 = i0; d0 = d; i0 = k; }
        else if (d < d1) { d2 = d1; i2 = i1; d1 = d;  i1 = k; }
        else if (d < d2) { d2 = d;  i2 = k; }
    }
#pragma unroll
    for (int m = 1; m <= 2; m <<= 1) {
        float e0 = __shfl_xor(d0, m, 64), e1 = __shfl_xor(d1, m, 64), e2 = __shfl_xor(d2, m, 64);
        int   j0 = __shfl_xor(i0, m, 64), j1 = __shfl_xor(i1, m, 64), j2 = __shfl_xor(i2, m, 64);
        float a0 = d0, a1 = d1, a2 = d2; int x0 = i0, x1 = i1, x2 = i2;
        float b0 = e0, b1 = e1, b2 = e2; int y0 = j0, y1 = j1, y2 = j2;
        bool tk = nn_less(a0, x0, b0, y0);
        d0 = tk ? a0 : b0; i0 = tk ? x0 : y0;
        float na0 = tk ? a1 : a0; int nx0 = tk ? x1 : x0;
        float na1 = tk ? a2 : a1; int nx1 = tk ? x2 : x1;
        float nb0 = tk ? b0 : b1; int ny0 = tk ? y0 : y1;
        float nb1 = tk ? b1 : b2; int ny1 = tk ? y1 : y2;
        tk = nn_less(na0, nx0, nb0, ny0);
        d1 = tk ? na0 : nb0; i1 = tk ? nx0 : ny0;
        float ma0 = tk ? na1 : na0; int mx0 = tk ? nx1 : nx0;
        float mb0 = tk ? nb0 : nb1; int my0 = tk ? ny0 : ny1;
        tk = nn_less(ma0, mx0, mb0, my0);
        d2 = tk ? ma0 : mb0; i2 = tk ? mx0 : my0;
    }
    if (q == 0) {
        float r0 = 1.0f / (d0 + 1e-8f), r1 = 1.0f / (d1 + 1e-8f), r2 = 1.0f / (d2 + 1e-8f);
        float norm = r0 + r1 + r2;
        size_t pg = (size_t)p;
        idx_out[pg * 3 + 0] = i0; idx_out[pg * 3 + 1] = i1; idx_out[pg * 3 + 2] = i2;
        w_out[pg * 3 + 0] = r0 / norm; w_out[pg * 3 + 1] = r1 / norm; w_out[pg * 3 + 2] = r2 / norm;
    }
}

// ---------------------------------------------------------------------------
// Mega-kernel device pieces
// ---------------------------------------------------------------------------
template <int K>
static __device__ __forceinline__ void gemm_lds(const char* smem, const unsigned short* Wp,
                                                int wv, int lhi, int llo, int lane,
                                                f32x4 acc[4][4]) {
#pragma unroll
    for (int i = 0; i < 4; ++i)
#pragma unroll
        for (int j = 0; j < 4; ++j) acc[i][j] = (f32x4){0.f, 0.f, 0.f, 0.f};
    const unsigned short* wbase = Wp + ((size_t)(wv * 256) + lane) * 8;
#pragma unroll
    for (int ks = 0; ks < K / 32; ++ks) {
        bf16x8 wf[4];
#pragma unroll
        for (int i = 0; i < 4; ++i)
            wf[i] = *(const bf16x8*)(wbase + (size_t)ks * 8192 + i * 512);
        bf16x8 bb[4];
#pragma unroll
        for (int j = 0; j < 4; ++j) {
            int row = j * 16 + llo;
            int cp  = (ks * 4 + lhi) ^ (row & 7);
            bb[j] = *(const bf16x8*)(smem + row * (K * 2) + cp * 16);
        }
#pragma unroll
        for (int i = 0; i < 4; ++i)
#pragma unroll
            for (int j = 0; j < 4; ++j)
                acc[i][j] = __builtin_amdgcn_mfma_f32_16x16x32_bf16(wf[i], bb[j], acc[i][j], 0, 0, 0);
    }
}

// add bias into acc, write per-block BN partials (sum/sumsq) to part[g][512]
static __device__ __forceinline__ void bias_stats(f32x4 acc[4][4], const float* bias_,
                                                  float* part, int g, int wv, int lhi, int llo) {
#pragma unroll
    for (int i = 0; i < 4; ++i) {
        int cbase = wv * 64 + i * 16 + lhi * 4;
        float4 bv = *(const float4*)(bias_ + cbase);
        float s0 = 0.f, s1 = 0.f, s2 = 0.f, s3 = 0.f;
        float q0 = 0.f, q1 = 0.f, q2 = 0.f, q3 = 0.f;
#pragma unroll
        for (int j = 0; j < 4; ++j) {
            acc[i][j][0] += bv.x; acc[i][j][1] += bv.y;
            acc[i][j][2] += bv.z; acc[i][j][3] += bv.w;
            s0 += acc[i][j][0]; q0 += acc[i][j][0] * acc[i][j][0];
            s1 += acc[i][j][1]; q1 += acc[i][j][1] * acc[i][j][1];
            s2 += acc[i][j][2]; q2 += acc[i][j][2] * acc[i][j][2];
            s3 += acc[i][j][3]; q3 += acc[i][j][3] * acc[i][j][3];
        }
#pragma unroll
        for (int m = 1; m <= 8; m <<= 1) {
            s0 += __shfl_xor(s0, m, 64); q0 += __shfl_xor(q0, m, 64);
            s1 += __shfl_xor(s1, m, 64); q1 += __shfl_xor(q1, m, 64);
            s2 += __shfl_xor(s2, m, 64); q2 += __shfl_xor(q2, m, 64);
            s3 += __shfl_xor(s3, m, 64); q3 += __shfl_xor(q3, m, 64);
        }
        if (llo == 0) {
            float* pb = part + (size_t)g * 512;
            astore(pb + cbase + 0, s0); astore(pb + cbase + 1, s1);
            astore(pb + cbase + 2, s2); astore(pb + cbase + 3, s3);
            astore(pb + 256 + cbase + 0, q0); astore(pb + 256 + cbase + 1, q1);
            astore(pb + 256 + cbase + 2, q2); astore(pb + 256 + cbase + 3, q3);
        }
    }
}

// write acc (bf16) into the 64x256 swizzled LDS image (512B rows)
static __device__ __forceinline__ void acc_to_lds(char* smem, const f32x4 acc[4][4],
                                                  int wv, int lhi, int llo) {
#pragma unroll
    for (int i = 0; i < 4; ++i) {
        int cbase = wv * 64 + i * 16 + lhi * 4;
        int c8 = cbase >> 3, hf = lhi & 1;
#pragma unroll
        for (int j = 0; j < 4; ++j) {
            int row = j * 16 + llo;
            unsigned lo = (unsigned)f2bf(acc[i][j][0]) | ((unsigned)f2bf(acc[i][j][1]) << 16);
            unsigned hi = (unsigned)f2bf(acc[i][j][2]) | ((unsigned)f2bf(acc[i][j][3]) << 16);
            uint2 o; o.x = lo; o.y = hi;
            *(uint2*)(smem + row * 512 + ((c8 ^ (row & 7)) << 4) + hf * 8) = o;
        }
    }
}

static __device__ __forceinline__ void reduce_stage(const float* part, float* partA, int g, int t) {
    if (g < 64) {
        float s = 0.f, q = 0.f;
#pragma unroll 4
        for (int i = 0; i < 16; ++i) {
            const float* pp = part + (size_t)(g * 16 + i) * 512;
            s += aload(pp + t); q += aload(pp + 256 + t);
        }
        astore(partA + g * 512 + t, s);
        astore(partA + g * 512 + 256 + t, q);
    }
}

static __device__ __forceinline__ void finalize_stage(const float* partA, const float* gamma,
                                                      const float* beta, float* affa, float* affc,
                                                      int g, int t) {
    if (g == 0) {
        float s = 0.f, q = 0.f;
#pragma unroll 8
        for (int i = 0; i < 64; ++i) {
            s += aload(partA + i * 512 + t);
            q += aload(partA + i * 512 + 256 + t);
        }
        float mean = s * (1.0f / PTOT);
        float var  = fmaxf(q * (1.0f / PTOT) - mean * mean, 0.0f);
        float a    = gamma[t] / sqrtf(var + 1e-5f);
        astore(affa + t, a);
        astore(affc + t, beta[t] - mean * a);
    }
}

// ---------------------------------------------------------------------------
// The persistent mega-kernel: 1024 blocks x 256 thr, co-resident (34KB LDS ->
// 4 blocks/CU = 1024 capacity; launch_bounds caps VGPR for 16 waves/CU).
// Activations never leave LDS; only BN stats cross global.
// ---------------------------------------------------------------------------
__global__ __launch_bounds__(256, 4) void k_mega(
        const float* __restrict__ ufeat,
        const unsigned short* __restrict__ kfT,
        const int* __restrict__ idxb, const float* __restrict__ wgtb,
        const unsigned short* __restrict__ Wub,
        const unsigned short* __restrict__ W1b,
        const unsigned short* __restrict__ W2b,
        const float* __restrict__ bu, const float* __restrict__ b1, const float* __restrict__ b2,
        const float* __restrict__ gu, const float* __restrict__ betau,
        const float* __restrict__ g1, const float* __restrict__ beta1,
        const float* __restrict__ g2, const float* __restrict__ beta2,
        float* part, float* partA,
        float* affa0, float* affc0, float* affa1, float* affc1, float* affa2, float* affc2,
        float* __restrict__ out, unsigned* bar) {
    __shared__ char  smem[32768];
    __shared__ float aff_lds[512];

    const int t    = threadIdx.x;
    const int g    = blockIdx.x;
    const int p0   = g * 64;
    const int b    = p0 >> 12;
    const int wv   = t >> 6;
    const int lane = t & 63;
    const int lhi  = lane >> 4, llo = lane & 15;

    f32x4 acc[4][4];

    // ---- P0: stage ufeat tile (64 pts x 128 ch) -> bf16 swizzled LDS ----
    {
        int c  = t >> 1;
        int ph = (t & 1) * 32;
        const float* src = ufeat + ((size_t)b * C1 + c) * NPTS + (p0 & 4095) + ph;
#pragma unroll
        for (int k = 0; k < 8; ++k) {
            float4 v = *(const float4*)(src + k * 4);
#pragma unroll
            for (int e = 0; e < 4; ++e) {
                int p = ph + k * 4 + e;
                float f = (e == 0) ? v.x : (e == 1) ? v.y : (e == 2) ? v.z : v.w;
                *(unsigned short*)(smem + p * 256 + ((((c >> 3) ^ (p & 7)) << 4) + (c & 7) * 2))
                    = f2bf(f);
            }
        }
    }
    __syncthreads();

    // ---- P1: gemm1 (K=128) + stats; y0 -> LDS ----
    gemm_lds<C1>(smem, Wub, wv, lhi, llo, lane, acc);
    bias_stats(acc, bu, part, g, wv, lhi, llo);
    __syncthreads();                  // all x1 reads done before overwrite
    acc_to_lds(smem, acc, wv, lhi, llo);
    gsync(bar);                       // #1

    // ---- P2: BN0 stats reduce + finalize ----
    reduce_stage(part, partA, g, t);
    gsync(bar);                       // #2
    finalize_stage(partA, gu, betau, affa0, affc0, g, t);
    gsync(bar);                       // #3

    // ---- P3: build_x in-place (interp gather + BN0(y0) skip) ----
    aff_lds[t]       = aload(affa0 + (t & 255));
    aff_lds[256 + (t & 255)] = (t < 256) ? aload(affc0 + t) : aff_lds[256 + (t & 255)];
    // simpler: two explicit loads
    if (t < 256) { aff_lds[t] = aload(affa0 + t); aff_lds[256 + t] = aload(affc0 + t); }
    __syncthreads();
    {
        int pj = t >> 2, q = t & 3;
        int p  = p0 + pj;
        int i0 = idxb[p * 3 + 0], i1 = idxb[p * 3 + 1], i2 = idxb[p * 3 + 2];
        float w0 = wgtb[p * 3 + 0], w1 = wgtb[p * 3 + 1], w2 = wgtb[p * 3 + 2];
        const unsigned short* kb = kfT + (size_t)b * MPTS * C2;
#pragma unroll
        for (int cc2 = 0; cc2 < 8; ++cc2) {
            int cc = q * 8 + cc2;
            int c0 = cc * 8;
            u32x4 v0 = *(const u32x4*)(kb + (size_t)i0 * C2 + c0);
            u32x4 v1 = *(const u32x4*)(kb + (size_t)i1 * C2 + c0);
            u32x4 v2 = *(const u32x4*)(kb + (size_t)i2 * C2 + c0);
            char* slot = smem + pj * 512 + ((cc ^ (pj & 7)) << 4);
            u32x4 vy = *(u32x4*)slot;
            unsigned r[4];
#pragma unroll
            for (int qq = 0; qq < 4; ++qq) {
                int c = c0 + qq * 2;
                float lo = w0 * bf2f(v0[qq] & 0xffff) + w1 * bf2f(v1[qq] & 0xffff)
                         + w2 * bf2f(v2[qq] & 0xffff)
                         + bf2f(vy[qq] & 0xffff) * aff_lds[c] + aff_lds[256 + c];
                float hi = w0 * bf2f(v0[qq] >> 16) + w1 * bf2f(v1[qq] >> 16)
                         + w2 * bf2f(v2[qq] >> 16)
                         + bf2f(vy[qq] >> 16) * aff_lds[c + 1] + aff_lds[256 + c + 1];
                r[qq] = (unsigned)f2bf(lo) | ((unsigned)f2bf(hi) << 16);
            }
            u32x4 vo; vo.x = r[0]; vo.y = r[1]; vo.z = r[2]; vo.w = r[3];
            *(u32x4*)slot = vo;
        }
    }
    __syncthreads();

    // ---- P4: gemm2 (K=256) + stats ----
    gemm_lds<C2>(smem, W1b, wv, lhi, llo, lane, acc);
    bias_stats(acc, b1, part, g, wv, lhi, llo);
    gsync(bar);                       // #4
    reduce_stage(part, partA, g, t);
    gsync(bar);                       // #5
    finalize_stage(partA, g1, beta1, affa1, affc1, g, t);
    gsync(bar);                       // #6

    // ---- P6: y1' = relu(BN1(y1)) -> LDS ----
    if (t < 256) { aff_lds[t] = aload(affa1 + t); aff_lds[256 + t] = aload(affc1 + t); }
    __syncthreads();
#pragma unroll
    for (int i = 0; i < 4; ++i) {
        int cbase = wv * 64 + i * 16 + lhi * 4;
        float4 la = *(const float4*)(aff_lds + cbase);
        float4 lc = *(const float4*)(aff_lds + 256 + cbase);
#pragma unroll
        for (int j = 0; j < 4; ++j) {
            acc[i][j][0] = fmaxf(acc[i][j][0] * la.x + lc.x, 0.f);
            acc[i][j][1] = fmaxf(acc[i][j][1] * la.y + lc.y, 0.f);
            acc[i][j][2] = fmaxf(acc[i][j][2] * la.z + lc.z, 0.f);
            acc[i][j][3] = fmaxf(acc[i][j][3] * la.w + lc.w, 0.f);
        }
    }
    acc_to_lds(smem, acc, wv, lhi, llo);
    __syncthreads();

    // ---- P7: gemm3 (K=256) + stats ----
    gemm_lds<C2>(smem, W2b, wv, lhi, llo, lane, acc);
    bias_stats(acc, b2, part, g, wv, lhi, llo);
    gsync(bar);                       // #7
    reduce_stage(part, partA, g, t);
    gsync(bar);                       // #8
    finalize_stage(partA, g2, beta2, affa2, affc2, g, t);
    gsync(bar);                       // #9

    // ---- P9: out = relu(BN2(y2)) transposed to (B,256,n) f32, 2 halves ----
    if (t < 256) { aff_lds[t] = aload(affa2 + t); aff_lds[256 + t] = aload(affc2 + t); }
    __syncthreads();
#pragma unroll
    for (int H = 0; H < 2; ++H) {
        if ((wv >> 1) == H) {
#pragma unroll
            for (int i = 0; i < 4; ++i) {
                int cbase = wv * 64 + i * 16 + lhi * 4;
                int cl = cbase - H * 128;
                float4 la = *(const float4*)(aff_lds + cbase);
                float4 lc = *(const float4*)(aff_lds + 256 + cbase);
#pragma unroll
                for (int j = 0; j < 4; ++j) {
                    int p = j * 16 + llo;
                    float* dstl = (float*)smem;
                    dstl[(cl + 0) * 64 + p] = fmaxf(acc[i][j][0] * la.x + lc.x, 0.f);
                    dstl[(cl + 1) * 64 + p] = fmaxf(acc[i][j][1] * la.y + lc.y, 0.f);
                    dstl[(cl + 2) * 64 + p] = fmaxf(acc[i][j][2] * la.z + lc.z, 0.f);
                    dstl[(cl + 3) * 64 + p] = fmaxf(acc[i][j][3] * la.w + lc.w, 0.f);
                }
            }
        }
        __syncthreads();
        {
            int c  = t >> 1;
            int hp = (t & 1) * 32;
            float* dst = out + ((size_t)b * 256 + H * 128 + c) * 4096 + (p0 & 4095) + hp;
            const float* srcl = (const float*)smem + c * 64 + hp;
#pragma unroll
            for (int k = 0; k < 8; ++k)
                *(float4*)(dst + k * 4) = *(const float4*)(srcl + k * 4);
        }
        __syncthreads();
    }
}

// ---------------------------------------------------------------------------
extern "C" void kernel_launch(void* const* d_in, const int* in_sizes, int n_in,
                              void* d_out, int out_size, void* d_ws, size_t ws_size,
                              hipStream_t stream) {
    const float* unknown = (const float*)d_in[0];
    const float* known   = (const float*)d_in[1];
    const float* ufeat   = (const float*)d_in[2];
    const float* kfeat   = (const float*)d_in[3];
    const float* Wu      = (const float*)d_in[4];
    const float* bu      = (const float*)d_in[5];
    const float* gu      = (const float*)d_in[6];
    const float* betau   = (const float*)d_in[7];
    const float* W1      = (const float*)d_in[8];
    const float* b1      = (const float*)d_in[9];
    const float* g1      = (const float*)d_in[10];
    const float* beta1   = (const float*)d_in[11];
    const float* W2      = (const float*)d_in[12];
    const float* b2      = (const float*)d_in[13];
    const float* g2      = (const float*)d_in[14];
    const float* beta2   = (const float*)d_in[15];
    float* out = (float*)d_out;

    char* ws = (char*)d_ws;
    unsigned short* kfT = (unsigned short*)ws;                           // 8MB
    unsigned short* Wub = (unsigned short*)(ws + ((size_t)8 << 20));     // 64KB
    unsigned short* W1b = Wub + 256 * 128;                               // 128KB
    unsigned short* W2b = W1b + 256 * 256;                               // 128KB
    int*   idxb = (int*)(W2b + 256 * 256);                               // 768KB
    float* wgtb = (float*)(idxb + (size_t)PTOT * 3);                     // 768KB
    float* part  = (float*)(ws + ((size_t)12 << 20));                    // 2MB
    float* partA = part + (size_t)NBLK * 512;                            // 128KB
    float* affa0 = partA + 64 * 512;
    float* affc0 = affa0 + 256;
    float* affa1 = affc0 + 256;
    float* affc1 = affa1 + 256;
    float* affa2 = affc1 + 256;
    float* affc2 = affa2 + 256;
    unsigned* bar = (unsigned*)(ws + ((size_t)15 << 20));                // 4KB
    if (ws_size < ((size_t)16 << 20)) return;

    // barrier counters must start at 0 (ws is poisoned 0xAA before timing)
    hipMemsetAsync(bar, 0, 4096, stream);

    // prep: kfT transpose, weight packs, three_nn
    k_transpose0<<<dim3(MPTS / 64, C2 / 64, BATCH), 256, 0, stream>>>(kfeat, kfT, C2, MPTS);
    k_cvt_pack<<<128, 256, 0, stream>>>(Wu, Wub, 128);
    k_cvt_pack<<<256, 256, 0, stream>>>(W1, W1b, 256);
    k_cvt_pack<<<256, 256, 0, stream>>>(W2, W2b, 256);
    k_three_nn<<<PTOT / 64, 256, 0, stream>>>(unknown, known, idxb, wgtb);

    // the fused pipeline
    k_mega<<<NBLK, 256, 0, stream>>>(ufeat, kfT, idxb, wgtb, Wub, W1b, W2b,
                                     bu, b1, b2, gu, betau, g1, beta1, g2, beta2,
                                     part, partA, affa0, affc0, affa1, affc1, affa2, affc2,
                                     out, bar);

    (void)in_sizes; (void)n_in; (void)out_size;
}

// Round 12
// 208.957 us; speedup vs baseline: 7.7148x; 7.7148x over previous
//
#include <hip/hip_runtime.h>
#include <hip/hip_bf16.h>
#include <cstddef>
#include <cstdint>

#define BATCH 16
#define NPTS  4096
#define MPTS  1024
#define PTOT  65536
#define C1    128
#define C2    256

typedef short bf16x8 __attribute__((ext_vector_type(8)));
typedef float f32x4  __attribute__((ext_vector_type(4)));
typedef unsigned int u32x4 __attribute__((ext_vector_type(4)));

static __device__ __forceinline__ float bf2f(unsigned int u16) {
    union { unsigned int i; float f; } v; v.i = u16 << 16; return v.f;
}
static __device__ __forceinline__ unsigned short f2bf(float f) {
    union { float f; unsigned int i; } v; v.f = f;
    unsigned int u = v.i;
    return (unsigned short)((u + 0x7FFFu + ((u >> 16) & 1u)) >> 16);
}

// ---------------------------------------------------------------------------
// Write-through stores (sc0 sc1): leave no dirty lines in the producer XCD's
// L2 — data lands clean in L3, so consumer first-touch reads are L3 hits
// instead of remote-dirty-L2 coherence round-trips (r10 probe evidence).
// ---------------------------------------------------------------------------
static __device__ __forceinline__ void st_wt_b128(void* p, u32x4 v) {
    asm volatile("global_store_dwordx4 %0, %1, off sc0 sc1" :: "v"(p), "v"(v) : "memory");
}
static __device__ __forceinline__ void st_wt_f128(void* p, f32x4 v) {
    asm volatile("global_store_dwordx4 %0, %1, off sc0 sc1" :: "v"(p), "v"(v) : "memory");
}
static __device__ __forceinline__ void st_wt_b64(void* p, uint2 v) {
    asm volatile("global_store_dwordx2 %0, %1, off sc0 sc1" :: "v"(p), "v"(v) : "memory");
}
static __device__ __forceinline__ void st_wt_b32(void* p, unsigned v) {
    asm volatile("global_store_dword %0, %1, off sc0 sc1" :: "v"(p), "v"(v) : "memory");
}
static __device__ __forceinline__ void st_wt_b16(void* p, unsigned v) {
    asm volatile("global_store_short %0, %1, off sc0 sc1" :: "v"(p), "v"(v) : "memory");
}

// ---------------------------------------------------------------------------
// Transpose (B, C, N) f32 -> (B, N, C) bf16. SWZ=1: chunk-swizzled rows.
// ---------------------------------------------------------------------------
template <int SWZ>
__global__ void k_transpose(const float* __restrict__ in, unsigned short* __restrict__ out,
                            int C, int N) {
    __shared__ float tile[64][65];
    int b  = blockIdx.z;
    int n0 = blockIdx.x * 64;
    int c0 = blockIdx.y * 64;
    const float* src = in + (size_t)b * C * N;
    unsigned short* dst = out + (size_t)b * N * C;
    int t  = threadIdx.x;
    int t4 = t >> 6;
    int tn = t & 63;
#pragma unroll
    for (int i = 0; i < 16; ++i) {
        int cc = i * 4 + t4;
        tile[cc][tn] = src[(size_t)(c0 + cc) * N + n0 + tn];
    }
    __syncthreads();
#pragma unroll
    for (int i = 0; i < 16; ++i) {
        int nn = i * 4 + t4;
        int p  = n0 + nn;
        int c  = c0 + tn;
        size_t off;
        if (SWZ) off = (size_t)p * C + (size_t)((((c >> 3) ^ (p & 7)) << 3) + (c & 7));
        else     off = (size_t)p * C + c;
        st_wt_b16(dst + off, (unsigned)f2bf(tile[tn][nn]));
    }
}

// ---------------------------------------------------------------------------
// Weight pack: (256, K) f32 -> bf16 fragment-packed [K/32][16][64 lane][8].
// ---------------------------------------------------------------------------
__global__ void k_cvt_pack(const float* __restrict__ in, unsigned short* __restrict__ out, int K) {
    int tid = blockIdx.x * 256 + threadIdx.x;
    if (tid >= 256 * K) return;
    int ch = tid / K, k = tid % K;
    int ks = k >> 5, lhi = (k >> 3) & 3, e = k & 7;
    int wv = ch >> 6, i = (ch >> 4) & 3, llo = ch & 15;
    int lane = lhi * 16 + llo;
    st_wt_b16(out + ((size_t)((ks * 16 + wv * 4 + i) * 64 + lane)) * 8 + e,
              (unsigned)f2bf(in[tid]));
}

// ---------------------------------------------------------------------------
// three_nn: 4 threads/point, chunked scan + shfl_xor butterfly merge.
// ---------------------------------------------------------------------------
static __device__ __forceinline__ bool nn_less(float da, int ia, float db, int ib) {
    return (da < db) || (da == db && ia < ib);
}

__global__ void k_three_nn(const float* __restrict__ unknown, const float* __restrict__ known,
                           int* __restrict__ idx_out, float* __restrict__ w_out) {
    __shared__ float4 kpt[MPTS + 4];
    int t  = threadIdx.x;
    int p0 = blockIdx.x * 64;
    int b  = p0 >> 12;
    const float* kb = known + (size_t)b * MPTS * 3;
    for (int i = t; i < MPTS; i += 256) {
        float x = kb[i * 3 + 0], y = kb[i * 3 + 1], z = kb[i * 3 + 2];
        float dd = __fadd_rn(__fadd_rn(__fmul_rn(x, x), __fmul_rn(y, y)), __fmul_rn(z, z));
        float4 v; v.x = x; v.y = y; v.z = z; v.w = dd;
        kpt[i + (i >> 8)] = v;
    }
    __syncthreads();

    int q = t & 3;
    int p = p0 + (t >> 2);
    const float* up = unknown + (size_t)p * 3;
    float ux = up[0], uy = up[1], uz = up[2];
    float u2 = __fadd_rn(__fadd_rn(__fmul_rn(ux, ux), __fmul_rn(uy, uy)), __fmul_rn(uz, uz));

    float d0 = INFINITY, d1 = INFINITY, d2 = INFINITY;
    int   i0 = 0, i1 = 0, i2 = 0;
    int base = q * 257;
#pragma unroll 4
    for (int it = 0; it < 256; ++it) {
        float4 kp = kpt[base + it];
        float dot = __fadd_rn(__fadd_rn(__fmul_rn(ux, kp.x), __fmul_rn(uy, kp.y)),
                              __fmul_rn(uz, kp.z));
        float d = __fsub_rn(__fadd_rn(u2, kp.w), __fmul_rn(2.0f, dot));
        int k = q * 256 + it;
        if (d < d0)      { d2 = d1; i2 = i1; d1 = d0; i1 = i0; d0 = d; i0 = k; }
        else if (d < d1) { d2 = d1; i2 = i1; d1 = d;  i1 = k; }
        else if (d < d2) { d2 = d;  i2 = k; }
    }

#pragma unroll
    for (int m = 1; m <= 2; m <<= 1) {
        float e0 = __shfl_xor(d0, m, 64), e1 = __shfl_xor(d1, m, 64), e2 = __shfl_xor(d2, m, 64);
        int   j0 = __shfl_xor(i0, m, 64), j1 = __shfl_xor(i1, m, 64), j2 = __shfl_xor(i2, m, 64);
        float a0 = d0, a1 = d1, a2 = d2; int x0 = i0, x1 = i1, x2 = i2;
        float b0 = e0, b1 = e1, b2 = e2; int y0 = j0, y1 = j1, y2 = j2;
        bool tk = nn_less(a0, x0, b0, y0);
        d0 = tk ? a0 : b0; i0 = tk ? x0 : y0;
        float na0 = tk ? a1 : a0; int nx0 = tk ? x1 : x0;
        float na1 = tk ? a2 : a1; int nx1 = tk ? x2 : x1;
        float nb0 = tk ? b0 : b1; int ny0 = tk ? y0 : y1;
        float nb1 = tk ? b1 : b2; int ny1 = tk ? y1 : y2;
        tk = nn_less(na0, nx0, nb0, ny0);
        d1 = tk ? na0 : nb0; i1 = tk ? nx0 : ny0;
        float ma0 = tk ? na1 : na0; int mx0 = tk ? nx1 : nx0;
        float mb0 = tk ? nb0 : nb1; int my0 = tk ? ny0 : ny1;
        tk = nn_less(ma0, mx0, mb0, my0);
        d2 = tk ? ma0 : mb0; i2 = tk ? mx0 : my0;
    }

    if (q == 0) {
        float r0 = 1.0f / (d0 + 1e-8f), r1 = 1.0f / (d1 + 1e-8f), r2 = 1.0f / (d2 + 1e-8f);
        float norm = r0 + r1 + r2;
        size_t pg = (size_t)p;
        st_wt_b32(idx_out + pg * 3 + 0, (unsigned)i0);
        st_wt_b32(idx_out + pg * 3 + 1, (unsigned)i1);
        st_wt_b32(idx_out + pg * 3 + 2, (unsigned)i2);
        union { float f; unsigned u; } w0v, w1v, w2v;
        w0v.f = r0 / norm; w1v.f = r1 / norm; w2v.f = r2 / norm;
        st_wt_b32(w_out + pg * 3 + 0, w0v.u);
        st_wt_b32(w_out + pg * 3 + 1, w1v.u);
        st_wt_b32(w_out + pg * 3 + 2, w2v.u);
    }
}

// ---------------------------------------------------------------------------
// GEMM (r6 structure): gload_lds staging, packed weight ping-pong, shfl
// stats, LDS-relayout Y store — all producer stores now write-through.
// ---------------------------------------------------------------------------
template <int K, int APPLY>
__global__ void k_gemm(
        const unsigned short* __restrict__ Wp,
        const unsigned short* __restrict__ X,
        const float* __restrict__ bias,
        const float* __restrict__ aff_a,
        const float* __restrict__ aff_c,
        unsigned short* __restrict__ Y,
        float* __restrict__ partial) {
    constexpr int NK = K / 32;
    constexpr int TILE_BYTES = 64 * K * 2;
    constexpr int SMEM_BYTES = TILE_BYTES > 32768 ? TILE_BYTES : 32768;
    __shared__ char smem[SMEM_BYTES];

    const int t    = threadIdx.x;
    const int p0   = blockIdx.x * 64;
    const int wv   = t >> 6;
    const int lane = t & 63;
    const int lhi  = lane >> 4, llo = lane & 15;

    if (!APPLY) {
        const char* src = (const char*)(X + (size_t)p0 * K);
        constexpr int ITERS = TILE_BYTES / (256 * 16);
#pragma unroll
        for (int i = 0; i < ITERS; ++i) {
            int off = (i * 256 + t) * 16;
            __builtin_amdgcn_global_load_lds(
                (const __attribute__((address_space(1))) unsigned int*)(src + off),
                (__attribute__((address_space(3))) unsigned int*)(smem + off),
                16, 0, 0);
        }
    } else {
        constexpr int CPR = K / 8;
#pragma unroll
        for (int i = 0; i < (64 * CPR) / 256; ++i) {
            int f   = i * 256 + t;
            int row = f / CPR, qp = f % CPR;
            int col = qp ^ (row & 7);
            uint4 v = *(const uint4*)(X + (size_t)(p0 + row) * K + qp * 8);
            unsigned int w[4] = {v.x, v.y, v.z, v.w};
            float4 a0 = *(const float4*)(aff_a + col * 8);
            float4 a1 = *(const float4*)(aff_a + col * 8 + 4);
            float4 cc0 = *(const float4*)(aff_c + col * 8);
            float4 cc1 = *(const float4*)(aff_c + col * 8 + 4);
            float aa[8] = {a0.x, a0.y, a0.z, a0.w, a1.x, a1.y, a1.z, a1.w};
            float cc[8] = {cc0.x, cc0.y, cc0.z, cc0.w, cc1.x, cc1.y, cc1.z, cc1.w};
#pragma unroll
            for (int q2 = 0; q2 < 4; ++q2) {
                float lo = fmaxf(bf2f(w[q2] & 0xffff) * aa[q2 * 2]     + cc[q2 * 2],     0.0f);
                float hi = fmaxf(bf2f(w[q2] >> 16)    * aa[q2 * 2 + 1] + cc[q2 * 2 + 1], 0.0f);
                w[q2] = (unsigned int)f2bf(lo) | ((unsigned int)f2bf(hi) << 16);
            }
            uint4 o; o.x = w[0]; o.y = w[1]; o.z = w[2]; o.w = w[3];
            *(uint4*)(smem + row * (K * 2) + qp * 16) = o;
        }
    }

    const unsigned short* wbase = Wp + ((size_t)(wv * 256) + lane) * 8;
    bf16x8 wA[4], wB[4];
#pragma unroll
    for (int i = 0; i < 4; ++i)
        wA[i] = *(const bf16x8*)(wbase + i * 512);

    __syncthreads();

    f32x4 acc[4][4];
#pragma unroll
    for (int i = 0; i < 4; ++i)
#pragma unroll
        for (int j = 0; j < 4; ++j) acc[i][j] = (f32x4){0.f, 0.f, 0.f, 0.f};

#pragma unroll
    for (int ks = 0; ks < NK; ks += 2) {
#pragma unroll
        for (int i = 0; i < 4; ++i)
            wB[i] = *(const bf16x8*)(wbase + (size_t)(ks + 1) * 8192 + i * 512);
        {
            bf16x8 bb[4];
#pragma unroll
            for (int j = 0; j < 4; ++j) {
                int row = j * 16 + llo;
                int cp  = (ks * 4 + lhi) ^ (row & 7);
                bb[j] = *(const bf16x8*)(smem + row * (K * 2) + cp * 16);
            }
#pragma unroll
            for (int i = 0; i < 4; ++i)
#pragma unroll
                for (int j = 0; j < 4; ++j)
                    acc[i][j] = __builtin_amdgcn_mfma_f32_16x16x32_bf16(wA[i], bb[j], acc[i][j], 0, 0, 0);
        }
        if (ks + 2 < NK) {
#pragma unroll
            for (int i = 0; i < 4; ++i)
                wA[i] = *(const bf16x8*)(wbase + (size_t)(ks + 2) * 8192 + i * 512);
        }
        {
            bf16x8 bb[4];
#pragma unroll
            for (int j = 0; j < 4; ++j) {
                int row = j * 16 + llo;
                int cp  = ((ks + 1) * 4 + lhi) ^ (row & 7);
                bb[j] = *(const bf16x8*)(smem + row * (K * 2) + cp * 16);
            }
#pragma unroll
            for (int i = 0; i < 4; ++i)
#pragma unroll
                for (int j = 0; j < 4; ++j)
                    acc[i][j] = __builtin_amdgcn_mfma_f32_16x16x32_bf16(wB[i], bb[j], acc[i][j], 0, 0, 0);
        }
    }

    __syncthreads();
#pragma unroll
    for (int i = 0; i < 4; ++i) {
        int cbase = wv * 64 + i * 16 + lhi * 4;
        float4 bv = *(const float4*)(bias + cbase);
        int c8 = cbase >> 3, hf = lhi & 1;
        float s0 = 0.f, s1 = 0.f, s2 = 0.f, s3 = 0.f;
        float q0 = 0.f, q1 = 0.f, q2 = 0.f, q3 = 0.f;
#pragma unroll
        for (int j = 0; j < 4; ++j) {
            int row = j * 16 + llo;
            float y0 = acc[i][j][0] + bv.x;
            float y1 = acc[i][j][1] + bv.y;
            float y2 = acc[i][j][2] + bv.z;
            float y3 = acc[i][j][3] + bv.w;
            s0 += y0; q0 += y0 * y0;  s1 += y1; q1 += y1 * y1;
            s2 += y2; q2 += y2 * y2;  s3 += y3; q3 += y3 * y3;
            unsigned int lo = (unsigned int)f2bf(y0) | ((unsigned int)f2bf(y1) << 16);
            unsigned int hi = (unsigned int)f2bf(y2) | ((unsigned int)f2bf(y3) << 16);
            uint2 o; o.x = lo; o.y = hi;
            *(uint2*)(smem + row * 512 + ((c8 ^ (row & 7)) << 4) + hf * 8) = o;
        }
#pragma unroll
        for (int m = 1; m <= 8; m <<= 1) {
            s0 += __shfl_xor(s0, m, 64); q0 += __shfl_xor(q0, m, 64);
            s1 += __shfl_xor(s1, m, 64); q1 += __shfl_xor(q1, m, 64);
            s2 += __shfl_xor(s2, m, 64); q2 += __shfl_xor(q2, m, 64);
            s3 += __shfl_xor(s3, m, 64); q3 += __shfl_xor(q3, m, 64);
        }
        if (llo == 0) {
            f32x4 sv = {s0, s1, s2, s3};
            f32x4 qv = {q0, q1, q2, q3};
            st_wt_f128(partial + (size_t)blockIdx.x * 512 + cbase, sv);
            st_wt_f128(partial + (size_t)blockIdx.x * 512 + 256 + cbase, qv);
        }
    }
    __syncthreads();
    {
        const char* ysrc = smem + wv * 8192 + lane * 16;
        char* ydst = (char*)(Y + (size_t)p0 * 256) + wv * 8192 + lane * 16;
#pragma unroll
        for (int i2 = 0; i2 < 8; ++i2) {
            u32x4 v = *(const u32x4*)(ysrc + i2 * 1024);
            st_wt_b128(ydst + i2 * 1024, v);
        }
    }
}

// ---------------------------------------------------------------------------
// Stats reduce: 1024 block-partials -> 64 -> affine(a,c)
// ---------------------------------------------------------------------------
__global__ void k_red1(const float* __restrict__ partial, float* __restrict__ partA) {
    int t = threadIdx.x, g = blockIdx.x;
    float s = 0.f, q = 0.f;
#pragma unroll
    for (int i = 0; i < 16; ++i) {
        const float* pp = partial + (size_t)(g * 16 + i) * 512;
        s += pp[t]; q += pp[256 + t];
    }
    union { float f; unsigned u; } sv, qv; sv.f = s; qv.f = q;
    st_wt_b32(partA + g * 512 + t, sv.u);
    st_wt_b32(partA + g * 512 + 256 + t, qv.u);
}

__global__ void k_finalize(const float* __restrict__ partA, const float* __restrict__ gamma,
                           const float* __restrict__ beta, float* __restrict__ aff_a,
                           float* __restrict__ aff_c) {
    int c = threadIdx.x;
    float s = 0.f, q = 0.f;
#pragma unroll 8
    for (int i = 0; i < 64; ++i) { s += partA[i * 512 + c]; q += partA[i * 512 + 256 + c]; }
    float mean = s * (1.0f / PTOT);
    float var  = fmaxf(q * (1.0f / PTOT) - mean * mean, 0.0f);
    float a    = gamma[c] / sqrtf(var + 1e-5f);
    union { float f; unsigned u; } av, cv;
    av.f = a; cv.f = beta[c] - mean * a;
    st_wt_b32(aff_a + c, av.u);
    st_wt_b32(aff_c + c, cv.u);
}

// ---------------------------------------------------------------------------
// x[p][c] = sum_j w_j * kfT[b][idx_j][c] + (y0[p][c]*a0[c] + c0[c])
// ---------------------------------------------------------------------------
__global__ void k_build_x(const unsigned short* __restrict__ y0, const unsigned short* __restrict__ kfT,
                          const int* __restrict__ idx, const float* __restrict__ wgt,
                          const float* __restrict__ aff_a, const float* __restrict__ aff_c,
                          unsigned short* __restrict__ X) {
    int t   = threadIdx.x;
    int p   = blockIdx.x * 8 + (t >> 5);
    int col = t & 31;
    int c0  = col * 8;
    int b   = p >> 12;
    int pos = col ^ (p & 7);
    int i0 = idx[p * 3 + 0], i1 = idx[p * 3 + 1], i2 = idx[p * 3 + 2];
    float w0 = wgt[p * 3 + 0], w1 = wgt[p * 3 + 1], w2 = wgt[p * 3 + 2];
    const size_t kb = (size_t)b * MPTS * C2;
    uint4 v0 = *(const uint4*)(kfT + kb + (size_t)i0 * C2 + c0);
    uint4 v1 = *(const uint4*)(kfT + kb + (size_t)i1 * C2 + c0);
    uint4 v2 = *(const uint4*)(kfT + kb + (size_t)i2 * C2 + c0);
    uint4 vy = *(const uint4*)(y0 + (size_t)p * C2 + pos * 8);
    const unsigned int* u0 = (const unsigned int*)&v0;
    const unsigned int* u1 = (const unsigned int*)&v1;
    const unsigned int* u2 = (const unsigned int*)&v2;
    const unsigned int* uy = (const unsigned int*)&vy;
    unsigned int r[4];
#pragma unroll
    for (int q = 0; q < 4; ++q) {
        int c = c0 + q * 2;
        float lo = w0 * bf2f(u0[q] & 0xffff) + w1 * bf2f(u1[q] & 0xffff) + w2 * bf2f(u2[q] & 0xffff)
                 + bf2f(uy[q] & 0xffff) * aff_a[c] + aff_c[c];
        float hi = w0 * bf2f(u0[q] >> 16) + w1 * bf2f(u1[q] >> 16) + w2 * bf2f(u2[q] >> 16)
                 + bf2f(uy[q] >> 16) * aff_a[c + 1] + aff_c[c + 1];
        r[q] = (unsigned int)f2bf(lo) | ((unsigned int)f2bf(hi) << 16);
    }
    u32x4 vout; vout.x = r[0]; vout.y = r[1]; vout.z = r[2]; vout.w = r[3];
    st_wt_b128(X + (size_t)p * C2 + pos * 8, vout);
}

// ---------------------------------------------------------------------------
// Final: out(B,256,n) f32 = relu(y2*a2+c2), from swizzled (P,256) bf16.
// ---------------------------------------------------------------------------
__global__ void k_final(const unsigned short* __restrict__ Y2, const float* __restrict__ aff_a,
                        const float* __restrict__ aff_c, float* __restrict__ out) {
    __shared__ float tile[64][65];
    int p0 = blockIdx.x * 64;
    int c0 = blockIdx.y * 64;
    int t  = threadIdx.x;
    int t4 = t >> 6, t64 = t & 63;
#pragma unroll
    for (int i = 0; i < 16; ++i) {
        int r = i * 4 + t4;
        int p = p0 + r;
        int c = c0 + t64;
        float v = bf2f(Y2[(size_t)p * 256 + (((c >> 3) ^ (p & 7)) << 3) + (c & 7)])
                  * aff_a[c] + aff_c[c];
        tile[t64][r] = fmaxf(v, 0.0f);
    }
    __syncthreads();
    int b   = p0 >> 12;
    int pin = p0 & 4095;
#pragma unroll
    for (int i = 0; i < 16; ++i) {
        int cc = i * 4 + t4;
        __builtin_nontemporal_store(tile[cc][t64],
            out + ((size_t)b * 256 + c0 + cc) * 4096 + pin + t64);
    }
}

// ---------------------------------------------------------------------------
extern "C" void kernel_launch(void* const* d_in, const int* in_sizes, int n_in,
                              void* d_out, int out_size, void* d_ws, size_t ws_size,
                              hipStream_t stream) {
    const float* unknown = (const float*)d_in[0];
    const float* known   = (const float*)d_in[1];
    const float* ufeat   = (const float*)d_in[2];
    const float* kfeat   = (const float*)d_in[3];
    const float* Wu      = (const float*)d_in[4];
    const float* bu      = (const float*)d_in[5];
    const float* gu      = (const float*)d_in[6];
    const float* betau   = (const float*)d_in[7];
    const float* W1      = (const float*)d_in[8];
    const float* b1      = (const float*)d_in[9];
    const float* g1      = (const float*)d_in[10];
    const float* beta1   = (const float*)d_in[11];
    const float* W2      = (const float*)d_in[12];
    const float* b2      = (const float*)d_in[13];
    const float* g2      = (const float*)d_in[14];
    const float* beta2   = (const float*)d_in[15];
    float* out = (float*)d_out;

    char* ws = (char*)d_ws;
    unsigned short* reg0 = (unsigned short*)ws;                        // 32MB: uT -> x -> y2
    unsigned short* ybuf = (unsigned short*)(ws + ((size_t)32 << 20)); // 32MB: y0 -> y1
    unsigned short* kfT  = (unsigned short*)(ws + ((size_t)64 << 20)); // 8MB
    unsigned short* Wub  = (unsigned short*)(ws + ((size_t)72 << 20)); // 64KB (packed)
    unsigned short* W1b  = Wub + 256 * 128;                            // 128KB (packed)
    unsigned short* W2b  = W1b + 256 * 256;                            // 128KB (packed)
    int*   idxb = (int*)(W2b + 256 * 256);                             // 768KB
    float* wgtb = (float*)(idxb + (size_t)PTOT * 3);                   // 768KB
    float* affa0 = wgtb + (size_t)PTOT * 3;
    float* affc0 = affa0 + 256;
    float* affa1 = affc0 + 256;
    float* affc1 = affa1 + 256;
    float* affa2 = affc1 + 256;
    float* affc2 = affa2 + 256;
    float* part0  = (float*)(ws + ((size_t)16 << 20));                 // 2MB (inside reg0)
    float* partA0 = (float*)(ws + ((size_t)18 << 20));                 // 128KB
    float* part12  = (float*)(ws + ((size_t)64 << 20));                // 2MB (kfT region, dead after build_x)
    float* partA12 = (float*)(ws + ((size_t)66 << 20));                // 128KB
    if (ws_size < ((size_t)75 << 20)) return;

    // 1) layout prep
    k_transpose<1><<<dim3(NPTS / 64, C1 / 64, BATCH), 256, 0, stream>>>(ufeat, reg0, C1, NPTS);
    k_transpose<0><<<dim3(MPTS / 64, C2 / 64, BATCH), 256, 0, stream>>>(kfeat, kfT, C2, MPTS);
    k_cvt_pack<<<128, 256, 0, stream>>>(Wu, Wub, 128);
    k_cvt_pack<<<256, 256, 0, stream>>>(W1, W1b, 256);
    k_cvt_pack<<<256, 256, 0, stream>>>(W2, W2b, 256);

    // 2) three_nn
    k_three_nn<<<PTOT / 64, 256, 0, stream>>>(unknown, known, idxb, wgtb);

    // 3) y0 = Wu @ uT + bu (stats fused)
    k_gemm<C1, 0><<<PTOT / 64, 256, 0, stream>>>(Wub, reg0, bu, nullptr, nullptr, ybuf, part0);
    k_red1<<<64, 256, 0, stream>>>(part0, partA0);
    k_finalize<<<1, 256, 0, stream>>>(partA0, gu, betau, affa0, affc0);

    // 4) x = interpolate + BN(y0)
    k_build_x<<<PTOT / 8, 256, 0, stream>>>(ybuf, kfT, idxb, wgtb, affa0, affc0, reg0);

    // 5) y1 = W1 @ x + b1 (stats fused)
    k_gemm<C2, 0><<<PTOT / 64, 256, 0, stream>>>(W1b, reg0, b1, nullptr, nullptr, ybuf, part12);
    k_red1<<<64, 256, 0, stream>>>(part12, partA12);
    k_finalize<<<1, 256, 0, stream>>>(partA12, g1, beta1, affa1, affc1);

    // 6) y2 = W2 @ relu(BN(y1)) + b2 (stats fused)
    k_gemm<C2, 1><<<PTOT / 64, 256, 0, stream>>>(W2b, ybuf, b2, affa1, affc1, reg0, part12);
    k_red1<<<64, 256, 0, stream>>>(part12, partA12);
    k_finalize<<<1, 256, 0, stream>>>(partA12, g2, beta2, affa2, affc2);

    // 7) out
    k_final<<<dim3(PTOT / 64, 4), 256, 0, stream>>>(reg0, affa2, affc2, out);

    (void)in_sizes; (void)n_in; (void)out_size;
}

// Round 13
// 201.493 us; speedup vs baseline: 8.0006x; 1.0370x over previous
//
#include <hip/hip_runtime.h>
#include <hip/hip_bf16.h>
#include <cstddef>
#include <cstdint>

#define BATCH 16
#define NPTS  4096
#define MPTS  1024
#define PTOT  65536
#define C1    128
#define C2    256

typedef short bf16x8 __attribute__((ext_vector_type(8)));
typedef float f32x4  __attribute__((ext_vector_type(4)));
typedef unsigned int u32x4 __attribute__((ext_vector_type(4)));

static __device__ __forceinline__ float bf2f(unsigned int u16) {
    union { unsigned int i; float f; } v; v.i = u16 << 16; return v.f;
}
static __device__ __forceinline__ unsigned short f2bf(float f) {
    union { float f; unsigned int i; } v; v.f = f;
    unsigned int u = v.i;
    return (unsigned short)((u + 0x7FFFu + ((u >> 16) & 1u)) >> 16);
}

// write-through stores (kept from r12; neutral-to-positive)
static __device__ __forceinline__ void st_wt_b128(void* p, u32x4 v) {
    asm volatile("global_store_dwordx4 %0, %1, off sc0 sc1" :: "v"(p), "v"(v) : "memory");
}
static __device__ __forceinline__ void st_wt_f128(void* p, f32x4 v) {
    asm volatile("global_store_dwordx4 %0, %1, off sc0 sc1" :: "v"(p), "v"(v) : "memory");
}
static __device__ __forceinline__ void st_wt_b32(void* p, unsigned v) {
    asm volatile("global_store_dword %0, %1, off sc0 sc1" :: "v"(p), "v"(v) : "memory");
}
static __device__ __forceinline__ void st_wt_b16(void* p, unsigned v) {
    asm volatile("global_store_short %0, %1, off sc0 sc1" :: "v"(p), "v"(v) : "memory");
}

// ---------------------------------------------------------------------------
// Transpose (B, C, N) f32 -> (B, N, C) bf16 (linear; kfT only now)
// ---------------------------------------------------------------------------
template <int SWZ>
__global__ void k_transpose(const float* __restrict__ in, unsigned short* __restrict__ out,
                            int C, int N) {
    __shared__ float tile[64][65];
    int b  = blockIdx.z;
    int n0 = blockIdx.x * 64;
    int c0 = blockIdx.y * 64;
    const float* src = in + (size_t)b * C * N;
    unsigned short* dst = out + (size_t)b * N * C;
    int t  = threadIdx.x;
    int t4 = t >> 6;
    int tn = t & 63;
#pragma unroll
    for (int i = 0; i < 16; ++i) {
        int cc = i * 4 + t4;
        tile[cc][tn] = src[(size_t)(c0 + cc) * N + n0 + tn];
    }
    __syncthreads();
#pragma unroll
    for (int i = 0; i < 16; ++i) {
        int nn = i * 4 + t4;
        int p  = n0 + nn;
        int c  = c0 + tn;
        size_t off;
        if (SWZ) off = (size_t)p * C + (size_t)((((c >> 3) ^ (p & 7)) << 3) + (c & 7));
        else     off = (size_t)p * C + c;
        st_wt_b16(dst + off, (unsigned)f2bf(tile[tn][nn]));
    }
}

// ---------------------------------------------------------------------------
// Weight pack: (256, K) f32 -> bf16 fragment-packed [K/32][16][64 lane][8].
// ---------------------------------------------------------------------------
__global__ void k_cvt_pack(const float* __restrict__ in, unsigned short* __restrict__ out, int K) {
    int tid = blockIdx.x * 256 + threadIdx.x;
    if (tid >= 256 * K) return;
    int ch = tid / K, k = tid % K;
    int ks = k >> 5, lhi = (k >> 3) & 3, e = k & 7;
    int wv = ch >> 6, i = (ch >> 4) & 3, llo = ch & 15;
    int lane = lhi * 16 + llo;
    st_wt_b16(out + ((size_t)((ks * 16 + wv * 4 + i) * 64 + lane)) * 8 + e,
              (unsigned)f2bf(in[tid]));
}

// ---------------------------------------------------------------------------
// three_nn (unchanged)
// ---------------------------------------------------------------------------
static __device__ __forceinline__ bool nn_less(float da, int ia, float db, int ib) {
    return (da < db) || (da == db && ia < ib);
}

__global__ void k_three_nn(const float* __restrict__ unknown, const float* __restrict__ known,
                           int* __restrict__ idx_out, float* __restrict__ w_out) {
    __shared__ float4 kpt[MPTS + 4];
    int t  = threadIdx.x;
    int p0 = blockIdx.x * 64;
    int b  = p0 >> 12;
    const float* kb = known + (size_t)b * MPTS * 3;
    for (int i = t; i < MPTS; i += 256) {
        float x = kb[i * 3 + 0], y = kb[i * 3 + 1], z = kb[i * 3 + 2];
        float dd = __fadd_rn(__fadd_rn(__fmul_rn(x, x), __fmul_rn(y, y)), __fmul_rn(z, z));
        float4 v; v.x = x; v.y = y; v.z = z; v.w = dd;
        kpt[i + (i >> 8)] = v;
    }
    __syncthreads();

    int q = t & 3;
    int p = p0 + (t >> 2);
    const float* up = unknown + (size_t)p * 3;
    float ux = up[0], uy = up[1], uz = up[2];
    float u2 = __fadd_rn(__fadd_rn(__fmul_rn(ux, ux), __fmul_rn(uy, uy)), __fmul_rn(uz, uz));

    float d0 = INFINITY, d1 = INFINITY, d2 = INFINITY;
    int   i0 = 0, i1 = 0, i2 = 0;
    int base = q * 257;
#pragma unroll 4
    for (int it = 0; it < 256; ++it) {
        float4 kp = kpt[base + it];
        float dot = __fadd_rn(__fadd_rn(__fmul_rn(ux, kp.x), __fmul_rn(uy, kp.y)),
                              __fmul_rn(uz, kp.z));
        float d = __fsub_rn(__fadd_rn(u2, kp.w), __fmul_rn(2.0f, dot));
        int k = q * 256 + it;
        if (d < d0)      { d2 = d1; i2 = i1; d1 = d0; i1 = i0; d0 = d; i0 = k; }
        else if (d < d1) { d2 = d1; i2 = i1; d1 = d;  i1 = k; }
        else if (d < d2) { d2 = d;  i2 = k; }
    }

#pragma unroll
    for (int m = 1; m <= 2; m <<= 1) {
        float e0 = __shfl_xor(d0, m, 64), e1 = __shfl_xor(d1, m, 64), e2 = __shfl_xor(d2, m, 64);
        int   j0 = __shfl_xor(i0, m, 64), j1 = __shfl_xor(i1, m, 64), j2 = __shfl_xor(i2, m, 64);
        float a0 = d0, a1 = d1, a2 = d2; int x0 = i0, x1 = i1, x2 = i2;
        float b0 = e0, b1 = e1, b2 = e2; int y0 = j0, y1 = j1, y2 = j2;
        bool tk = nn_less(a0, x0, b0, y0);
        d0 = tk ? a0 : b0; i0 = tk ? x0 : y0;
        float na0 = tk ? a1 : a0; int nx0 = tk ? x1 : x0;
        float na1 = tk ? a2 : a1; int nx1 = tk ? x2 : x1;
        float nb0 = tk ? b0 : b1; int ny0 = tk ? y0 : y1;
        float nb1 = tk ? b1 : b2; int ny1 = tk ? y1 : y2;
        tk = nn_less(na0, nx0, nb0, ny0);
        d1 = tk ? na0 : nb0; i1 = tk ? nx0 : ny0;
        float ma0 = tk ? na1 : na0; int mx0 = tk ? nx1 : nx0;
        float mb0 = tk ? nb0 : nb1; int my0 = tk ? ny0 : ny1;
        tk = nn_less(ma0, mx0, mb0, my0);
        d2 = tk ? ma0 : mb0; i2 = tk ? mx0 : my0;
    }

    if (q == 0) {
        float r0 = 1.0f / (d0 + 1e-8f), r1 = 1.0f / (d1 + 1e-8f), r2 = 1.0f / (d2 + 1e-8f);
        float norm = r0 + r1 + r2;
        size_t pg = (size_t)p;
        st_wt_b32(idx_out + pg * 3 + 0, (unsigned)i0);
        st_wt_b32(idx_out + pg * 3 + 1, (unsigned)i1);
        st_wt_b32(idx_out + pg * 3 + 2, (unsigned)i2);
        union { float f; unsigned u; } w0v, w1v, w2v;
        w0v.f = r0 / norm; w1v.f = r1 / norm; w2v.f = r2 / norm;
        st_wt_b32(w_out + pg * 3 + 0, w0v.u);
        st_wt_b32(w_out + pg * 3 + 1, w1v.u);
        st_wt_b32(w_out + pg * 3 + 2, w2v.u);
    }
}

// ---------------------------------------------------------------------------
// GEMM. MODE 0: gload_lds from bf16 swizzled X (fresh d_ws).
//       MODE 1: manual staging + BN/relu apply (bf16 X).
//       MODE 2: transpose-stage DIRECTLY from f32 d_in (B,C1,N) — kills the
//               uT intermediate; tests the d_in-vs-fresh axis on GEMM1.
// ---------------------------------------------------------------------------
template <int K, int MODE>
__global__ void k_gemm(
        const unsigned short* __restrict__ Wp,
        const unsigned short* __restrict__ X,
        const float* __restrict__ Xf,
        const float* __restrict__ bias,
        const float* __restrict__ aff_a,
        const float* __restrict__ aff_c,
        unsigned short* __restrict__ Y,
        float* __restrict__ partial) {
    constexpr int NK = K / 32;
    constexpr int TILE_BYTES = 64 * K * 2;
    constexpr int SMEM_BYTES = TILE_BYTES > 32768 ? TILE_BYTES : 32768;
    __shared__ char smem[SMEM_BYTES];

    const int t    = threadIdx.x;
    const int p0   = blockIdx.x * 64;
    const int wv   = t >> 6;
    const int lane = t & 63;
    const int lhi  = lane >> 4, llo = lane & 15;

    if (MODE == 0) {
        const char* src = (const char*)(X + (size_t)p0 * K);
        constexpr int ITERS = TILE_BYTES / (256 * 16);
#pragma unroll
        for (int i = 0; i < ITERS; ++i) {
            int off = (i * 256 + t) * 16;
            __builtin_amdgcn_global_load_lds(
                (const __attribute__((address_space(1))) unsigned int*)(src + off),
                (__attribute__((address_space(3))) unsigned int*)(smem + off),
                16, 0, 0);
        }
    } else if (MODE == 1) {
        constexpr int CPR = K / 8;
#pragma unroll
        for (int i = 0; i < (64 * CPR) / 256; ++i) {
            int f   = i * 256 + t;
            int row = f / CPR, qp = f % CPR;
            int col = qp ^ (row & 7);
            uint4 v = *(const uint4*)(X + (size_t)(p0 + row) * K + qp * 8);
            unsigned int w[4] = {v.x, v.y, v.z, v.w};
            float4 a0 = *(const float4*)(aff_a + col * 8);
            float4 a1 = *(const float4*)(aff_a + col * 8 + 4);
            float4 cc0 = *(const float4*)(aff_c + col * 8);
            float4 cc1 = *(const float4*)(aff_c + col * 8 + 4);
            float aa[8] = {a0.x, a0.y, a0.z, a0.w, a1.x, a1.y, a1.z, a1.w};
            float cc[8] = {cc0.x, cc0.y, cc0.z, cc0.w, cc1.x, cc1.y, cc1.z, cc1.w};
#pragma unroll
            for (int q2 = 0; q2 < 4; ++q2) {
                float lo = fmaxf(bf2f(w[q2] & 0xffff) * aa[q2 * 2]     + cc[q2 * 2],     0.0f);
                float hi = fmaxf(bf2f(w[q2] >> 16)    * aa[q2 * 2 + 1] + cc[q2 * 2 + 1], 0.0f);
                w[q2] = (unsigned int)f2bf(lo) | ((unsigned int)f2bf(hi) << 16);
            }
            uint4 o; o.x = w[0]; o.y = w[1]; o.z = w[2]; o.w = w[3];
            *(uint4*)(smem + row * (K * 2) + qp * 16) = o;
        }
    } else {
        // MODE 2 (K=128 only): stage from f32 (B, C1, N) d_in directly.
        // Thread: channel c = t>>1, n-half ph = (t&1)*32; reads 256B-contig
        // rows, writes bf16 scalars into the chunk-swizzled LDS image.
        // Verified in r11 (P0).
        int c  = t >> 1;
        int ph = (t & 1) * 32;
        int b  = p0 >> 12;
        const float* src = Xf + ((size_t)b * C1 + c) * NPTS + (p0 & 4095) + ph;
#pragma unroll
        for (int k = 0; k < 8; ++k) {
            float4 v = *(const float4*)(src + k * 4);
#pragma unroll
            for (int e = 0; e < 4; ++e) {
                int p = ph + k * 4 + e;
                float f = (e == 0) ? v.x : (e == 1) ? v.y : (e == 2) ? v.z : v.w;
                *(unsigned short*)(smem + p * (K * 2) + ((((c >> 3) ^ (p & 7)) << 4) + (c & 7) * 2))
                    = f2bf(f);
            }
        }
    }

    const unsigned short* wbase = Wp + ((size_t)(wv * 256) + lane) * 8;
    bf16x8 wA[4], wB[4];
#pragma unroll
    for (int i = 0; i < 4; ++i)
        wA[i] = *(const bf16x8*)(wbase + i * 512);

    __syncthreads();

    f32x4 acc[4][4];
#pragma unroll
    for (int i = 0; i < 4; ++i)
#pragma unroll
        for (int j = 0; j < 4; ++j) acc[i][j] = (f32x4){0.f, 0.f, 0.f, 0.f};

#pragma unroll
    for (int ks = 0; ks < NK; ks += 2) {
#pragma unroll
        for (int i = 0; i < 4; ++i)
            wB[i] = *(const bf16x8*)(wbase + (size_t)(ks + 1) * 8192 + i * 512);
        {
            bf16x8 bb[4];
#pragma unroll
            for (int j = 0; j < 4; ++j) {
                int row = j * 16 + llo;
                int cp  = (ks * 4 + lhi) ^ (row & 7);
                bb[j] = *(const bf16x8*)(smem + row * (K * 2) + cp * 16);
            }
#pragma unroll
            for (int i = 0; i < 4; ++i)
#pragma unroll
                for (int j = 0; j < 4; ++j)
                    acc[i][j] = __builtin_amdgcn_mfma_f32_16x16x32_bf16(wA[i], bb[j], acc[i][j], 0, 0, 0);
        }
        if (ks + 2 < NK) {
#pragma unroll
            for (int i = 0; i < 4; ++i)
                wA[i] = *(const bf16x8*)(wbase + (size_t)(ks + 2) * 8192 + i * 512);
        }
        {
            bf16x8 bb[4];
#pragma unroll
            for (int j = 0; j < 4; ++j) {
                int row = j * 16 + llo;
                int cp  = ((ks + 1) * 4 + lhi) ^ (row & 7);
                bb[j] = *(const bf16x8*)(smem + row * (K * 2) + cp * 16);
            }
#pragma unroll
            for (int i = 0; i < 4; ++i)
#pragma unroll
                for (int j = 0; j < 4; ++j)
                    acc[i][j] = __builtin_amdgcn_mfma_f32_16x16x32_bf16(wB[i], bb[j], acc[i][j], 0, 0, 0);
        }
    }

    __syncthreads();
#pragma unroll
    for (int i = 0; i < 4; ++i) {
        int cbase = wv * 64 + i * 16 + lhi * 4;
        float4 bv = *(const float4*)(bias + cbase);
        int c8 = cbase >> 3, hf = lhi & 1;
        float s0 = 0.f, s1 = 0.f, s2 = 0.f, s3 = 0.f;
        float q0 = 0.f, q1 = 0.f, q2 = 0.f, q3 = 0.f;
#pragma unroll
        for (int j = 0; j < 4; ++j) {
            int row = j * 16 + llo;
            float y0 = acc[i][j][0] + bv.x;
            float y1 = acc[i][j][1] + bv.y;
            float y2 = acc[i][j][2] + bv.z;
            float y3 = acc[i][j][3] + bv.w;
            s0 += y0; q0 += y0 * y0;  s1 += y1; q1 += y1 * y1;
            s2 += y2; q2 += y2 * y2;  s3 += y3; q3 += y3 * y3;
            unsigned int lo = (unsigned int)f2bf(y0) | ((unsigned int)f2bf(y1) << 16);
            unsigned int hi = (unsigned int)f2bf(y2) | ((unsigned int)f2bf(y3) << 16);
            uint2 o; o.x = lo; o.y = hi;
            *(uint2*)(smem + row * 512 + ((c8 ^ (row & 7)) << 4) + hf * 8) = o;
        }
#pragma unroll
        for (int m = 1; m <= 8; m <<= 1) {
            s0 += __shfl_xor(s0, m, 64); q0 += __shfl_xor(q0, m, 64);
            s1 += __shfl_xor(s1, m, 64); q1 += __shfl_xor(q1, m, 64);
            s2 += __shfl_xor(s2, m, 64); q2 += __shfl_xor(q2, m, 64);
            s3 += __shfl_xor(s3, m, 64); q3 += __shfl_xor(q3, m, 64);
        }
        if (llo == 0) {
            f32x4 sv = {s0, s1, s2, s3};
            f32x4 qv = {q0, q1, q2, q3};
            st_wt_f128(partial + (size_t)blockIdx.x * 512 + cbase, sv);
            st_wt_f128(partial + (size_t)blockIdx.x * 512 + 256 + cbase, qv);
        }
    }
    __syncthreads();
    {
        const char* ysrc = smem + wv * 8192 + lane * 16;
        char* ydst = (char*)(Y + (size_t)p0 * 256) + wv * 8192 + lane * 16;
#pragma unroll
        for (int i2 = 0; i2 < 8; ++i2) {
            u32x4 v = *(const u32x4*)(ysrc + i2 * 1024);
            st_wt_b128(ydst + i2 * 1024, v);
        }
    }
}

// ---------------------------------------------------------------------------
// Stats reduce: 1024 block-partials -> 64 -> affine(a,c)
// ---------------------------------------------------------------------------
__global__ void k_red1(const float* __restrict__ partial, float* __restrict__ partA) {
    int t = threadIdx.x, g = blockIdx.x;
    float s = 0.f, q = 0.f;
#pragma unroll
    for (int i = 0; i < 16; ++i) {
        const float* pp = partial + (size_t)(g * 16 + i) * 512;
        s += pp[t]; q += pp[256 + t];
    }
    union { float f; unsigned u; } sv, qv; sv.f = s; qv.f = q;
    st_wt_b32(partA + g * 512 + t, sv.u);
    st_wt_b32(partA + g * 512 + 256 + t, qv.u);
}

__global__ void k_finalize(const float* __restrict__ partA, const float* __restrict__ gamma,
                           const float* __restrict__ beta, float* __restrict__ aff_a,
                           float* __restrict__ aff_c) {
    int c = threadIdx.x;
    float s = 0.f, q = 0.f;
#pragma unroll 8
    for (int i = 0; i < 64; ++i) { s += partA[i * 512 + c]; q += partA[i * 512 + 256 + c]; }
    float mean = s * (1.0f / PTOT);
    float var  = fmaxf(q * (1.0f / PTOT) - mean * mean, 0.0f);
    float a    = gamma[c] / sqrtf(var + 1e-5f);
    union { float f; unsigned u; } av, cv;
    av.f = a; cv.f = beta[c] - mean * a;
    st_wt_b32(aff_a + c, av.u);
    st_wt_b32(aff_c + c, cv.u);
}

// ---------------------------------------------------------------------------
// build_x (unchanged control)
// ---------------------------------------------------------------------------
__global__ void k_build_x(const unsigned short* __restrict__ y0, const unsigned short* __restrict__ kfT,
                          const int* __restrict__ idx, const float* __restrict__ wgt,
                          const float* __restrict__ aff_a, const float* __restrict__ aff_c,
                          unsigned short* __restrict__ X) {
    int t   = threadIdx.x;
    int p   = blockIdx.x * 8 + (t >> 5);
    int col = t & 31;
    int c0  = col * 8;
    int b   = p >> 12;
    int pos = col ^ (p & 7);
    int i0 = idx[p * 3 + 0], i1 = idx[p * 3 + 1], i2 = idx[p * 3 + 2];
    float w0 = wgt[p * 3 + 0], w1 = wgt[p * 3 + 1], w2 = wgt[p * 3 + 2];
    const size_t kb = (size_t)b * MPTS * C2;
    uint4 v0 = *(const uint4*)(kfT + kb + (size_t)i0 * C2 + c0);
    uint4 v1 = *(const uint4*)(kfT + kb + (size_t)i1 * C2 + c0);
    uint4 v2 = *(const uint4*)(kfT + kb + (size_t)i2 * C2 + c0);
    uint4 vy = *(const uint4*)(y0 + (size_t)p * C2 + pos * 8);
    const unsigned int* u0 = (const unsigned int*)&v0;
    const unsigned int* u1 = (const unsigned int*)&v1;
    const unsigned int* u2 = (const unsigned int*)&v2;
    const unsigned int* uy = (const unsigned int*)&vy;
    unsigned int r[4];
#pragma unroll
    for (int q = 0; q < 4; ++q) {
        int c = c0 + q * 2;
        float lo = w0 * bf2f(u0[q] & 0xffff) + w1 * bf2f(u1[q] & 0xffff) + w2 * bf2f(u2[q] & 0xffff)
                 + bf2f(uy[q] & 0xffff) * aff_a[c] + aff_c[c];
        float hi = w0 * bf2f(u0[q] >> 16) + w1 * bf2f(u1[q] >> 16) + w2 * bf2f(u2[q] >> 16)
                 + bf2f(uy[q] >> 16) * aff_a[c + 1] + aff_c[c + 1];
        r[q] = (unsigned int)f2bf(lo) | ((unsigned int)f2bf(hi) << 16);
    }
    u32x4 vout; vout.x = r[0]; vout.y = r[1]; vout.z = r[2]; vout.w = r[3];
    st_wt_b128(X + (size_t)p * C2 + pos * 8, vout);
}

// ---------------------------------------------------------------------------
// Final (unchanged control)
// ---------------------------------------------------------------------------
__global__ void k_final(const unsigned short* __restrict__ Y2, const float* __restrict__ aff_a,
                        const float* __restrict__ aff_c, float* __restrict__ out) {
    __shared__ float tile[64][65];
    int p0 = blockIdx.x * 64;
    int c0 = blockIdx.y * 64;
    int t  = threadIdx.x;
    int t4 = t >> 6, t64 = t & 63;
#pragma unroll
    for (int i = 0; i < 16; ++i) {
        int r = i * 4 + t4;
        int p = p0 + r;
        int c = c0 + t64;
        float v = bf2f(Y2[(size_t)p * 256 + (((c >> 3) ^ (p & 7)) << 3) + (c & 7)])
                  * aff_a[c] + aff_c[c];
        tile[t64][r] = fmaxf(v, 0.0f);
    }
    __syncthreads();
    int b   = p0 >> 12;
    int pin = p0 & 4095;
#pragma unroll
    for (int i = 0; i < 16; ++i) {
        int cc = i * 4 + t4;
        __builtin_nontemporal_store(tile[cc][t64],
            out + ((size_t)b * 256 + c0 + cc) * 4096 + pin + t64);
    }
}

// ---------------------------------------------------------------------------
extern "C" void kernel_launch(void* const* d_in, const int* in_sizes, int n_in,
                              void* d_out, int out_size, void* d_ws, size_t ws_size,
                              hipStream_t stream) {
    const float* unknown = (const float*)d_in[0];
    const float* known   = (const float*)d_in[1];
    const float* ufeat   = (const float*)d_in[2];
    const float* kfeat   = (const float*)d_in[3];
    const float* Wu      = (const float*)d_in[4];
    const float* bu      = (const float*)d_in[5];
    const float* gu      = (const float*)d_in[6];
    const float* betau   = (const float*)d_in[7];
    const float* W1      = (const float*)d_in[8];
    const float* b1      = (const float*)d_in[9];
    const float* g1      = (const float*)d_in[10];
    const float* beta1   = (const float*)d_in[11];
    const float* W2      = (const float*)d_in[12];
    const float* b2      = (const float*)d_in[13];
    const float* g2      = (const float*)d_in[14];
    const float* beta2   = (const float*)d_in[15];
    float* out = (float*)d_out;

    char* ws = (char*)d_ws;
    unsigned short* reg0 = (unsigned short*)ws;                        // 32MB: x -> y2
    unsigned short* ybuf = (unsigned short*)(ws + ((size_t)32 << 20)); // 32MB: y0 -> y1
    unsigned short* kfT  = (unsigned short*)(ws + ((size_t)64 << 20)); // 8MB
    unsigned short* Wub  = (unsigned short*)(ws + ((size_t)72 << 20)); // 64KB (packed)
    unsigned short* W1b  = Wub + 256 * 128;                            // 128KB (packed)
    unsigned short* W2b  = W1b + 256 * 256;                            // 128KB (packed)
    int*   idxb = (int*)(W2b + 256 * 256);                             // 768KB
    float* wgtb = (float*)(idxb + (size_t)PTOT * 3);                   // 768KB
    float* affa0 = wgtb + (size_t)PTOT * 3;
    float* affc0 = affa0 + 256;
    float* affa1 = affc0 + 256;
    float* affc1 = affa1 + 256;
    float* affa2 = affc1 + 256;
    float* affc2 = affa2 + 256;
    float* part0  = (float*)(ws + ((size_t)16 << 20));                 // 2MB (reg0 region, free pre-build_x)
    float* partA0 = (float*)(ws + ((size_t)18 << 20));                 // 128KB
    float* part12  = (float*)(ws + ((size_t)64 << 20));                // 2MB (kfT region, dead after build_x)
    float* partA12 = (float*)(ws + ((size_t)66 << 20));                // 128KB
    if (ws_size < ((size_t)75 << 20)) return;

    // 1) layout prep (uT transpose eliminated — GEMM1 reads ufeat directly)
    k_transpose<0><<<dim3(MPTS / 64, C2 / 64, BATCH), 256, 0, stream>>>(kfeat, kfT, C2, MPTS);
    k_cvt_pack<<<128, 256, 0, stream>>>(Wu, Wub, 128);
    k_cvt_pack<<<256, 256, 0, stream>>>(W1, W1b, 256);
    k_cvt_pack<<<256, 256, 0, stream>>>(W2, W2b, 256);

    // 2) three_nn
    k_three_nn<<<PTOT / 64, 256, 0, stream>>>(unknown, known, idxb, wgtb);

    // 3) y0 = Wu @ ufeat + bu  (MODE 2: stage straight from d_in)
    k_gemm<C1, 2><<<PTOT / 64, 256, 0, stream>>>(Wub, nullptr, ufeat, bu, nullptr, nullptr,
                                                 ybuf, part0);
    k_red1<<<64, 256, 0, stream>>>(part0, partA0);
    k_finalize<<<1, 256, 0, stream>>>(partA0, gu, betau, affa0, affc0);

    // 4) x = interpolate + BN(y0)
    k_build_x<<<PTOT / 8, 256, 0, stream>>>(ybuf, kfT, idxb, wgtb, affa0, affc0, reg0);

    // 5) y1 = W1 @ x + b1 (MODE 0 control)
    k_gemm<C2, 0><<<PTOT / 64, 256, 0, stream>>>(W1b, reg0, nullptr, b1, nullptr, nullptr,
                                                 ybuf, part12);
    k_red1<<<64, 256, 0, stream>>>(part12, partA12);
    k_finalize<<<1, 256, 0, stream>>>(partA12, g1, beta1, affa1, affc1);

    // 6) y2 = W2 @ relu(BN(y1)) + b2 (MODE 1 control)
    k_gemm<C2, 1><<<PTOT / 64, 256, 0, stream>>>(W2b, ybuf, nullptr, b2, affa1, affc1,
                                                 reg0, part12);
    k_red1<<<64, 256, 0, stream>>>(part12, partA12);
    k_finalize<<<1, 256, 0, stream>>>(partA12, g2, beta2, affa2, affc2);

    // 7) out
    k_final<<<dim3(PTOT / 64, 4), 256, 0, stream>>>(reg0, affa2, affc2, out);

    (void)in_sizes; (void)n_in; (void)out_size;
}